// Round 2
// baseline (3208.391 us; speedup 1.0000x reference)
//
#include <hip/hip_runtime.h>
#include <cmath>

#define DEV static __device__ __forceinline__

DEV float leaky_f(float x) { return x > 0.f ? x : 0.2f * x; }

// ---------------- FiLM: gamma/beta from global features ----------------
__global__ void k_film(const float* __restrict__ gf,
                       const float* __restrict__ gW, const float* __restrict__ gb,
                       const float* __restrict__ bW, const float* __restrict__ bb,
                       float* __restrict__ out) {
  int j = threadIdx.x;
  if (j >= 64) return;
  float g = gb[j], b = bb[j];
  for (int k = 0; k < 128; ++k) {
    float v = gf[k];
    g += v * gW[k * 64 + j];
    b += v * bW[k * 64 + j];
  }
  out[j] = 1.0f + g;   // store (1+gamma)
  out[64 + j] = b;
}

// ---------------- input projection + FiLM ----------------
__global__ __launch_bounds__(256) void k_input(
    const float* __restrict__ nf, const float* __restrict__ ipW,
    const float* __restrict__ ipb, const float* __restrict__ gbv,
    float* __restrict__ x64, int N) {
  int lane = threadIdx.x & 63;
  int n = blockIdx.x * 4 + (threadIdx.x >> 6);
  if (n >= N) return;
  const float* row = nf + (size_t)n * 5;
  float acc = ipb[lane];
#pragma unroll
  for (int k = 0; k < 5; ++k) acc += row[k] * ipW[k * 64 + lane];
  acc = fmaxf(acc, 0.f);
  acc = acc * gbv[lane] + gbv[64 + lane];
  x64[(size_t)n * 64 + lane] = acc;
}

// ---------------- CSR build ----------------
__global__ void k_count(const int* __restrict__ dst, int* __restrict__ cnt, int E) {
  int e = blockIdx.x * 256 + threadIdx.x;
  if (e < E) atomicAdd(&cnt[dst[e]], 1);
}

__global__ void k_scan(const int* __restrict__ cnt, int* __restrict__ off, int N) {
  __shared__ int s[256];
  int tid = threadIdx.x;
  int carry = 0;
  for (int base = 0; base < N; base += 256) {
    int i = base + tid;
    int v = (i < N) ? cnt[i] : 0;
    __syncthreads();
    s[tid] = v;
    __syncthreads();
    int x = v;
    for (int d = 1; d < 256; d <<= 1) {
      int t = (tid >= d) ? s[tid - d] : 0;
      __syncthreads();
      x += t;
      s[tid] = x;
      __syncthreads();
    }
    if (i < N) off[i] = carry + x - v;  // exclusive scan
    carry += s[255];
  }
  if (tid == 0) off[N] = carry;
}

__global__ void k_scatter(const int* __restrict__ dst, const int* __restrict__ off,
                          int* __restrict__ cur, int* __restrict__ eid, int E) {
  int e = blockIdx.x * 256 + threadIdx.x;
  if (e < E) {
    int d = dst[e];
    int p = atomicAdd(&cur[d], 1);
    eid[off[d] + p] = e;
  }
}

// ---------------- edge encoder, writing directly in CSR order ----------------
__global__ __launch_bounds__(256) void k_edgefeat(
    const float* __restrict__ pos, const int* __restrict__ src, const int* __restrict__ dst,
    const int* __restrict__ eid,
    const float* __restrict__ W1, const float* __restrict__ b1,
    const float* __restrict__ W2, const float* __restrict__ b2,
    float* __restrict__ ef_csr, int* __restrict__ src_csr, int E) {
  __shared__ float sW1[160], sb1[32], sW2[1024], sb2[32];
  for (int i = threadIdx.x; i < 160; i += 256) sW1[i] = W1[i];
  for (int i = threadIdx.x; i < 1024; i += 256) sW2[i] = W2[i];
  if (threadIdx.x < 32) { sb1[threadIdx.x] = b1[threadIdx.x]; sb2[threadIdx.x] = b2[threadIdx.x]; }
  __syncthreads();
  int t = blockIdx.x * 256 + threadIdx.x;
  if (t >= E) return;
  int e = eid[t];
  int s = src[e], d = dst[e];
  src_csr[t] = s;
  float dx = pos[d * 3 + 0] - pos[s * 3 + 0];
  float dy = pos[d * 3 + 1] - pos[s * 3 + 1];
  float dz = pos[d * 3 + 2] - pos[s * 3 + 2];
  float dist = sqrtf(dx * dx + dy * dy + dz * dz);
  dist = fmaxf(dist, 1e-6f);
  float inv = 1.f / dist;
  float attr[5] = {dx * inv, dy * inv, dz * inv, dist, logf(dist)};
  float h[32];
#pragma unroll
  for (int j = 0; j < 32; ++j) {
    float a = sb1[j];
#pragma unroll
    for (int k = 0; k < 5; ++k) a += attr[k] * sW1[k * 32 + j];
    h[j] = fmaxf(a, 0.f);
  }
  float* o = ef_csr + (size_t)t * 32;
#pragma unroll 4
  for (int j = 0; j < 32; ++j) {
    float a = sb2[j];
#pragma unroll
    for (int k = 0; k < 32; ++k) a += h[k] * sW2[k * 32 + j];
    o[j] = a;
  }
}

// ---------------- tiled fp32 GEMM: C[M x 256] = A[M x K] @ B[K x 256] + bias ----------------
__global__ __launch_bounds__(256) void k_gemm(
    const float* __restrict__ A, const float* __restrict__ B,
    const float* __restrict__ bias, float* __restrict__ C, int M, int K) {
  __shared__ float As[16][64];
  __shared__ float Bs[16][68];
  int tid = threadIdx.x;
  int tx = tid & 15, ty = tid >> 4;
  int brow = blockIdx.x * 64, bcol = blockIdx.y * 64;
  float acc[4][4] = {};
  for (int k0 = 0; k0 < K; k0 += 16) {
    {
      int idx = tid * 4;
      int r = idx >> 4, kk = idx & 15;
      int row = brow + r; if (row > M - 1) row = M - 1;
      const float4 a4 = *(const float4*)(A + (size_t)row * K + k0 + kk);
      As[kk + 0][r] = a4.x; As[kk + 1][r] = a4.y; As[kk + 2][r] = a4.z; As[kk + 3][r] = a4.w;
    }
    {
      int kk = tid >> 4;
      int c = (tid & 15) * 4;
      const float4 b4 = *(const float4*)(B + (size_t)(k0 + kk) * 256 + bcol + c);
      *(float4*)(&Bs[kk][c]) = b4;
    }
    __syncthreads();
#pragma unroll
    for (int k = 0; k < 16; ++k) {
      float a[4], b[4];
#pragma unroll
      for (int i = 0; i < 4; ++i) a[i] = As[k][ty * 4 + i];
#pragma unroll
      for (int j = 0; j < 4; ++j) b[j] = Bs[k][tx * 4 + j];
#pragma unroll
      for (int i = 0; i < 4; ++i)
#pragma unroll
        for (int j = 0; j < 4; ++j) acc[i][j] += a[i] * b[j];
    }
    __syncthreads();
  }
#pragma unroll
  for (int i = 0; i < 4; ++i) {
    int row = brow + ty * 4 + i;
    if (row < M) {
      float4 r;
      r.x = acc[i][0] + bias[bcol + tx * 4 + 0];
      r.y = acc[i][1] + bias[bcol + tx * 4 + 1];
      r.z = acc[i][2] + bias[bcol + tx * 4 + 2];
      r.w = acc[i][3] + bias[bcol + tx * 4 + 3];
      *(float4*)(C + (size_t)row * 256 + bcol + tx * 4) = r;
    }
  }
}

// ---------------- fused: gate + logits + segment softmax + aggregate + LN + relu + residual
// one wave per dst node; lane holds channels {lane, 64+lane, 128+lane, 192+lane} = head {0,1,2,3}
__global__ __launch_bounds__(256) void k_fused(
    const int* __restrict__ off, const int* __restrict__ src_csr,
    const float* __restrict__ ef_csr,
    const float* __restrict__ xl, const float* __restrict__ xr,
    const float* __restrict__ xprev,
    const float* __restrict__ We_l, const float* __restrict__ att_l,
    const float* __restrict__ convb, const float* __restrict__ lng,
    const float* __restrict__ lnb,
    float* __restrict__ xout, int N) {
  int lane = threadIdx.x & 63;
  int n = blockIdx.x * 4 + (threadIdx.x >> 6);
  if (n >= N) return;
  // We columns for this lane's 4 channels, in registers (128 VGPR)
  float w0[32], w1[32], w2[32], w3[32];
#pragma unroll
  for (int j = 0; j < 32; ++j) {
    const float* Wr_ = We_l + (size_t)j * 256;
    w0[j] = Wr_[lane];
    w1[j] = Wr_[64 + lane];
    w2[j] = Wr_[128 + lane];
    w3[j] = Wr_[192 + lane];
  }
  float at0 = att_l[lane], at1 = att_l[64 + lane], at2 = att_l[128 + lane], at3 = att_l[192 + lane];
  const float* xrrow = xr + (size_t)n * 256;
  float xr0 = xrrow[lane], xr1 = xrrow[64 + lane], xr2 = xrrow[128 + lane], xr3 = xrrow[192 + lane];
  int o0 = off[n], o1 = off[n + 1];
  float m0 = -3.4e38f, m1 = m0, m2 = m0, m3 = m0;
  float s0 = 0.f, s1 = 0.f, s2 = 0.f, s3 = 0.f;
  float a0 = 0.f, a1 = 0.f, a2 = 0.f, a3 = 0.f;
  for (int t = o0; t < o1; ++t) {
    int sN = src_csr[t];
    const float* xlrow = xl + (size_t)sN * 256;
    float xl0 = xlrow[lane], xl1 = xlrow[64 + lane], xl2 = xlrow[128 + lane], xl3 = xlrow[192 + lane];
    const float4* efp = (const float4*)(ef_csr + (size_t)t * 32);
    float e0 = 0.f, e1 = 0.f, e2 = 0.f, e3 = 0.f;
#pragma unroll
    for (int j4 = 0; j4 < 8; ++j4) {
      float4 v = efp[j4];
      e0 += v.x * w0[4 * j4] + v.y * w0[4 * j4 + 1] + v.z * w0[4 * j4 + 2] + v.w * w0[4 * j4 + 3];
      e1 += v.x * w1[4 * j4] + v.y * w1[4 * j4 + 1] + v.z * w1[4 * j4 + 2] + v.w * w1[4 * j4 + 3];
      e2 += v.x * w2[4 * j4] + v.y * w2[4 * j4 + 1] + v.z * w2[4 * j4 + 2] + v.w * w2[4 * j4 + 3];
      e3 += v.x * w3[4 * j4] + v.y * w3[4 * j4 + 1] + v.z * w3[4 * j4 + 2] + v.w * w3[4 * j4 + 3];
    }
    float l0 = leaky_f(xl0 + xr0 + e0) * at0;
    float l1 = leaky_f(xl1 + xr1 + e1) * at1;
    float l2 = leaky_f(xl2 + xr2 + e2) * at2;
    float l3 = leaky_f(xl3 + xr3 + e3) * at3;
#pragma unroll
    for (int d = 1; d < 64; d <<= 1) {
      l0 += __shfl_xor(l0, d);
      l1 += __shfl_xor(l1, d);
      l2 += __shfl_xor(l2, d);
      l3 += __shfl_xor(l3, d);
    }
    // online softmax update, head q uses lane channel block q
    float nm, sc, wgt;
    nm = fmaxf(m0, l0); sc = __expf(m0 - nm); wgt = __expf(l0 - nm);
    s0 = s0 * sc + wgt; a0 = a0 * sc + wgt * xl0; m0 = nm;
    nm = fmaxf(m1, l1); sc = __expf(m1 - nm); wgt = __expf(l1 - nm);
    s1 = s1 * sc + wgt; a1 = a1 * sc + wgt * xl1; m1 = nm;
    nm = fmaxf(m2, l2); sc = __expf(m2 - nm); wgt = __expf(l2 - nm);
    s2 = s2 * sc + wgt; a2 = a2 * sc + wgt * xl2; m2 = nm;
    nm = fmaxf(m3, l3); sc = __expf(m3 - nm); wgt = __expf(l3 - nm);
    s3 = s3 * sc + wgt; a3 = a3 * sc + wgt * xl3; m3 = nm;
  }
  int deg = o1 - o0;
  float i0 = deg > 0 ? 1.f / s0 : 0.f;
  float i1 = deg > 0 ? 1.f / s1 : 0.f;
  float i2 = deg > 0 ? 1.f / s2 : 0.f;
  float i3 = deg > 0 ? 1.f / s3 : 0.f;
  float v0 = a0 * i0 + convb[lane];
  float v1 = a1 * i1 + convb[64 + lane];
  float v2 = a2 * i2 + convb[128 + lane];
  float v3 = a3 * i3 + convb[192 + lane];
  float ssum = v0 + v1 + v2 + v3;
  float ssq = v0 * v0 + v1 * v1 + v2 * v2 + v3 * v3;
#pragma unroll
  for (int d = 1; d < 64; d <<= 1) {
    ssum += __shfl_xor(ssum, d);
    ssq += __shfl_xor(ssq, d);
  }
  float mu = ssum * (1.0f / 256.0f);
  float var = ssq * (1.0f / 256.0f) - mu * mu;
  float rstd = rsqrtf(var + 1e-5f);
  const float* xp = xprev + (size_t)n * 256;
  float* xo = xout + (size_t)n * 256;
  xo[lane]       = fmaxf((v0 - mu) * rstd * lng[lane]       + lnb[lane],       0.f) + xp[lane];
  xo[64 + lane]  = fmaxf((v1 - mu) * rstd * lng[64 + lane]  + lnb[64 + lane],  0.f) + xp[64 + lane];
  xo[128 + lane] = fmaxf((v2 - mu) * rstd * lng[128 + lane] + lnb[128 + lane], 0.f) + xp[128 + lane];
  xo[192 + lane] = fmaxf((v3 - mu) * rstd * lng[192 + lane] + lnb[192 + lane], 0.f) + xp[192 + lane];
}

// ---------------- output projection ----------------
__global__ __launch_bounds__(256) void k_out(
    const float* __restrict__ x, const float* __restrict__ W1, const float* __restrict__ b1,
    const float* __restrict__ W2, const float* __restrict__ b2,
    float* __restrict__ out, int N) {
  __shared__ float sW1[256 * 64];  // 64 KB
  for (int i = threadIdx.x; i < 256 * 64; i += 256) sW1[i] = W1[i];
  __syncthreads();
  int lane = threadIdx.x & 63;
  int wv = threadIdx.x >> 6;
  for (int n = blockIdx.x * 4 + wv; n < N; n += gridDim.x * 4) {
    const float* xrow = x + (size_t)n * 256;
    float h = b1[lane];
    for (int k = 0; k < 256; ++k) h += xrow[k] * sW1[k * 64 + lane];
    h = fmaxf(h, 0.f);
    float y[5];
#pragma unroll
    for (int o = 0; o < 5; ++o) {
      float p = h * W2[lane * 5 + o];
#pragma unroll
      for (int d = 1; d < 64; d <<= 1) p += __shfl_xor(p, d);
      y[o] = p;
    }
    if (lane == 0) {
#pragma unroll
      for (int o = 0; o < 5; ++o) out[(size_t)n * 5 + o] = y[o] + b2[o];
    }
  }
}

extern "C" void kernel_launch(void* const* d_in, const int* in_sizes, int n_in,
                              void* d_out, int out_size, void* d_ws, size_t ws_size,
                              hipStream_t stream) {
  const float* nf      = (const float*)d_in[0];
  const float* gf      = (const float*)d_in[1];
  const int*   eidx    = (const int*)d_in[2];
  const float* pos     = (const float*)d_in[3];
  const float* ip_W    = (const float*)d_in[4];
  const float* ip_b    = (const float*)d_in[5];
  const float* film_gW = (const float*)d_in[6];
  const float* film_gb = (const float*)d_in[7];
  const float* film_bW = (const float*)d_in[8];
  const float* film_bb = (const float*)d_in[9];
  const float* ee_W1   = (const float*)d_in[10];
  const float* ee_b1   = (const float*)d_in[11];
  const float* ee_W2   = (const float*)d_in[12];
  const float* ee_b2   = (const float*)d_in[13];
  const float* res_W   = (const float*)d_in[14];
  const float* res_b   = (const float*)d_in[15];
  const float* l0_Wl   = (const float*)d_in[16];
  const float* l0_bl   = (const float*)d_in[17];
  const float* l0_Wr   = (const float*)d_in[18];
  const float* l0_br   = (const float*)d_in[19];
  const float* Wl      = (const float*)d_in[20];
  const float* bl      = (const float*)d_in[21];
  const float* Wr      = (const float*)d_in[22];
  const float* br      = (const float*)d_in[23];
  const float* We      = (const float*)d_in[24];
  const float* att     = (const float*)d_in[25];
  const float* conv_b  = (const float*)d_in[26];
  const float* ln_g    = (const float*)d_in[27];
  const float* ln_b    = (const float*)d_in[28];
  const float* op_W1   = (const float*)d_in[29];
  const float* op_b1   = (const float*)d_in[30];
  const float* op_W2   = (const float*)d_in[31];
  const float* op_b2   = (const float*)d_in[32];

  const int N = in_sizes[0] / 5;
  const int E = in_sizes[2] / 2;
  const int* src = eidx;
  const int* dst = eidx + E;

  float* ws = (float*)d_ws;
  size_t o = 0;
  auto alloc = [&](size_t nflt) {
    float* p = ws + o;
    o += (nflt + 63) & ~(size_t)63;
    return p;
  };
  float* gb      = alloc(128);
  float* x64     = alloc((size_t)N * 64);
  float* ef_csr  = alloc((size_t)E * 32);
  int*   src_csr = (int*)alloc((size_t)E);
  int*   cnt     = (int*)alloc(2 * (size_t)N);
  int*   cur     = cnt + N;
  int*   csroff  = (int*)alloc((size_t)N + 1);
  int*   csreid  = (int*)alloc((size_t)E);
  float* xl      = alloc((size_t)N * 256);
  float* xr      = alloc((size_t)N * 256);
  float* xA      = alloc((size_t)N * 256);
  float* xB      = alloc((size_t)N * 256);
  float* xp0     = alloc((size_t)N * 256);

  (void)ws_size; (void)n_in; (void)out_size;

  hipMemsetAsync(cnt, 0, 2 * (size_t)N * sizeof(int), stream);

  k_film<<<1, 64, 0, stream>>>(gf, film_gW, film_gb, film_bW, film_bb, gb);
  k_input<<<(N + 3) / 4, 256, 0, stream>>>(nf, ip_W, ip_b, gb, x64, N);
  k_count<<<(E + 255) / 256, 256, 0, stream>>>(dst, cnt, E);
  k_scan<<<1, 256, 0, stream>>>(cnt, csroff, N);
  k_scatter<<<(E + 255) / 256, 256, 0, stream>>>(dst, csroff, cur, csreid, E);
  k_edgefeat<<<(E + 255) / 256, 256, 0, stream>>>(pos, src, dst, csreid,
      ee_W1, ee_b1, ee_W2, ee_b2, ef_csr, src_csr, E);

  const float* xin = x64;
  for (int layer = 0; layer < 6; ++layer) {
    const int K = (layer == 0) ? 64 : 256;
    const float* Wl_p = (layer == 0) ? l0_Wl : (Wl + (size_t)(layer - 1) * 256 * 256);
    const float* bl_p = (layer == 0) ? l0_bl : (bl + (size_t)(layer - 1) * 256);
    const float* Wr_p = (layer == 0) ? l0_Wr : (Wr + (size_t)(layer - 1) * 256 * 256);
    const float* br_p = (layer == 0) ? l0_br : (br + (size_t)(layer - 1) * 256);

    dim3 gg((N + 63) / 64, 4);
    k_gemm<<<gg, 256, 0, stream>>>(xin, Wl_p, bl_p, xl, N, K);
    k_gemm<<<gg, 256, 0, stream>>>(xin, Wr_p, br_p, xr, N, K);

    const float* prev;
    if (layer == 0) {
      k_gemm<<<gg, 256, 0, stream>>>(xin, res_W, res_b, xp0, N, 64);
      prev = xp0;
    } else {
      prev = xin;
    }

    float* xout = (layer & 1) ? xB : xA;
    k_fused<<<(N + 3) / 4, 256, 0, stream>>>(
        csroff, src_csr, ef_csr, xl, xr, prev,
        We + (size_t)layer * 32 * 256, att + (size_t)layer * 256,
        conv_b + (size_t)layer * 256, ln_g + (size_t)layer * 256, ln_b + (size_t)layer * 256,
        xout, N);
    xin = xout;
  }

  k_out<<<512, 256, 0, stream>>>(xin, op_W1, op_b1, op_W2, op_b2, (float*)d_out, N);
}

// Round 3
// 1506.690 us; speedup vs baseline: 2.1294x; 2.1294x over previous
//
#include <hip/hip_runtime.h>
#include <cmath>

#define DEV static __device__ __forceinline__

DEV float leaky_f(float x) { return x > 0.f ? x : 0.2f * x; }

#define FMA4(A, sV, V) { (A).x += (sV)*(V).x; (A).y += (sV)*(V).y; (A).z += (sV)*(V).z; (A).w += (sV)*(V).w; }

// ---------------- FiLM: gamma/beta from global features ----------------
__global__ void k_film(const float* __restrict__ gf,
                       const float* __restrict__ gW, const float* __restrict__ gb,
                       const float* __restrict__ bW, const float* __restrict__ bb,
                       float* __restrict__ out) {
  int j = threadIdx.x;
  if (j >= 64) return;
  float g = gb[j], b = bb[j];
  for (int k = 0; k < 128; ++k) {
    float v = gf[k];
    g += v * gW[k * 64 + j];
    b += v * bW[k * 64 + j];
  }
  out[j] = 1.0f + g;   // store (1+gamma)
  out[64 + j] = b;
}

// ---------------- input projection + FiLM ----------------
__global__ __launch_bounds__(256) void k_input(
    const float* __restrict__ nf, const float* __restrict__ ipW,
    const float* __restrict__ ipb, const float* __restrict__ gbv,
    float* __restrict__ x64, int N) {
  int lane = threadIdx.x & 63;
  int n = blockIdx.x * 4 + (threadIdx.x >> 6);
  if (n >= N) return;
  const float* row = nf + (size_t)n * 5;
  float acc = ipb[lane];
#pragma unroll
  for (int k = 0; k < 5; ++k) acc += row[k] * ipW[k * 64 + lane];
  acc = fmaxf(acc, 0.f);
  acc = acc * gbv[lane] + gbv[64 + lane];
  x64[(size_t)n * 64 + lane] = acc;
}

// ---------------- CSR build ----------------
__global__ void k_count(const int* __restrict__ dst, int* __restrict__ cnt, int E) {
  int e = blockIdx.x * 256 + threadIdx.x;
  if (e < E) atomicAdd(&cnt[dst[e]], 1);
}

__global__ void k_scan(const int* __restrict__ cnt, int* __restrict__ off, int N) {
  __shared__ int s[256];
  int tid = threadIdx.x;
  int carry = 0;
  for (int base = 0; base < N; base += 256) {
    int i = base + tid;
    int v = (i < N) ? cnt[i] : 0;
    __syncthreads();
    s[tid] = v;
    __syncthreads();
    int x = v;
    for (int d = 1; d < 256; d <<= 1) {
      int t = (tid >= d) ? s[tid - d] : 0;
      __syncthreads();
      x += t;
      s[tid] = x;
      __syncthreads();
    }
    if (i < N) off[i] = carry + x - v;  // exclusive scan
    carry += s[255];
  }
  if (tid == 0) off[N] = carry;
}

__global__ void k_scatter(const int* __restrict__ dst, const int* __restrict__ off,
                          int* __restrict__ cur, int* __restrict__ eid, int E) {
  int e = blockIdx.x * 256 + threadIdx.x;
  if (e < E) {
    int d = dst[e];
    int p = atomicAdd(&cur[d], 1);
    eid[off[d] + p] = e;
  }
}

// ---------------- edge encoder, writing directly in CSR order ----------------
__global__ __launch_bounds__(256) void k_edgefeat(
    const float* __restrict__ pos, const int* __restrict__ src, const int* __restrict__ dst,
    const int* __restrict__ eid,
    const float* __restrict__ W1, const float* __restrict__ b1,
    const float* __restrict__ W2, const float* __restrict__ b2,
    float* __restrict__ ef_csr, int* __restrict__ src_csr, int E) {
  __shared__ float sW1[160], sb1[32], sW2[1024], sb2[32];
  for (int i = threadIdx.x; i < 160; i += 256) sW1[i] = W1[i];
  for (int i = threadIdx.x; i < 1024; i += 256) sW2[i] = W2[i];
  if (threadIdx.x < 32) { sb1[threadIdx.x] = b1[threadIdx.x]; sb2[threadIdx.x] = b2[threadIdx.x]; }
  __syncthreads();
  int t = blockIdx.x * 256 + threadIdx.x;
  if (t >= E) return;
  int e = eid[t];
  int s = src[e], d = dst[e];
  src_csr[t] = s;
  float dx = pos[d * 3 + 0] - pos[s * 3 + 0];
  float dy = pos[d * 3 + 1] - pos[s * 3 + 1];
  float dz = pos[d * 3 + 2] - pos[s * 3 + 2];
  float dist = sqrtf(dx * dx + dy * dy + dz * dz);
  dist = fmaxf(dist, 1e-6f);
  float inv = 1.f / dist;
  float attr[5] = {dx * inv, dy * inv, dz * inv, dist, logf(dist)};
  float h[32];
#pragma unroll
  for (int j = 0; j < 32; ++j) {
    float a = sb1[j];
#pragma unroll
    for (int k = 0; k < 5; ++k) a += attr[k] * sW1[k * 32 + j];
    h[j] = fmaxf(a, 0.f);
  }
  float* o = ef_csr + (size_t)t * 32;
#pragma unroll 4
  for (int j = 0; j < 32; ++j) {
    float a = sb2[j];
#pragma unroll
    for (int k = 0; k < 32; ++k) a += h[k] * sW2[k * 32 + j];
    o[j] = a;
  }
}

// ---------------- tiled fp32 GEMM: C[M x 256] = A[M x K] @ B[K x 256] + bias ----------------
__global__ __launch_bounds__(256) void k_gemm(
    const float* __restrict__ A, const float* __restrict__ B,
    const float* __restrict__ bias, float* __restrict__ C, int M, int K) {
  __shared__ float As[16][64];
  __shared__ float Bs[16][68];
  int tid = threadIdx.x;
  int tx = tid & 15, ty = tid >> 4;
  int brow = blockIdx.x * 64, bcol = blockIdx.y * 64;
  float acc[4][4] = {};
  for (int k0 = 0; k0 < K; k0 += 16) {
    {
      int idx = tid * 4;
      int r = idx >> 4, kk = idx & 15;
      int row = brow + r; if (row > M - 1) row = M - 1;
      const float4 a4 = *(const float4*)(A + (size_t)row * K + k0 + kk);
      As[kk + 0][r] = a4.x; As[kk + 1][r] = a4.y; As[kk + 2][r] = a4.z; As[kk + 3][r] = a4.w;
    }
    {
      int kk = tid >> 4;
      int c = (tid & 15) * 4;
      const float4 b4 = *(const float4*)(B + (size_t)(k0 + kk) * 256 + bcol + c);
      *(float4*)(&Bs[kk][c]) = b4;
    }
    __syncthreads();
#pragma unroll
    for (int k = 0; k < 16; ++k) {
      float a[4], b[4];
#pragma unroll
      for (int i = 0; i < 4; ++i) a[i] = As[k][ty * 4 + i];
#pragma unroll
      for (int j = 0; j < 4; ++j) b[j] = Bs[k][tx * 4 + j];
#pragma unroll
      for (int i = 0; i < 4; ++i)
#pragma unroll
        for (int j = 0; j < 4; ++j) acc[i][j] += a[i] * b[j];
    }
    __syncthreads();
  }
#pragma unroll
  for (int i = 0; i < 4; ++i) {
    int row = brow + ty * 4 + i;
    if (row < M) {
      float4 r;
      r.x = acc[i][0] + bias[bcol + tx * 4 + 0];
      r.y = acc[i][1] + bias[bcol + tx * 4 + 1];
      r.z = acc[i][2] + bias[bcol + tx * 4 + 2];
      r.w = acc[i][3] + bias[bcol + tx * 4 + 3];
      *(float4*)(C + (size_t)row * 256 + bcol + tx * 4) = r;
    }
  }
}

// ---------------- fused GATv2 layer: gate+logits+softmax+aggregate+LN+relu+residual
// one wave per dst node. lane owns 4 CONTIGUOUS channels of one head:
//   h = lane>>4, c0 = lane&15, channels ch0..ch0+3 where ch0 = h*64 + 4*c0.
// logit reduce = 16-lane butterfly (4 shfl); softmax state scalar per lane.
__global__ __launch_bounds__(256) void k_fused(
    const int* __restrict__ off, const int* __restrict__ src_csr,
    const float* __restrict__ ef_csr,
    const float* __restrict__ xl, const float* __restrict__ xr,
    const float* __restrict__ xprev,
    const float* __restrict__ We_l, const float* __restrict__ att_l,
    const float* __restrict__ convb, const float* __restrict__ lng,
    const float* __restrict__ lnb,
    float* __restrict__ xout, int N) {
  int lane = threadIdx.x & 63;
  int n = blockIdx.x * 4 + (threadIdx.x >> 6);
  if (n >= N) return;
  n = __builtin_amdgcn_readfirstlane(n);  // wave-uniform -> scalar CSR/ef loads
  int h = lane >> 4, c0 = lane & 15;
  int ch0 = h * 64 + (c0 << 2);
  // We columns for this lane's 4 channels: w4[k] = We[k][ch0..ch0+3]
  float4 w4[32];
#pragma unroll
  for (int k = 0; k < 32; ++k) w4[k] = *(const float4*)(We_l + k * 256 + ch0);
  float4 att4 = *(const float4*)(att_l + ch0);
  float4 xr4 = *(const float4*)(xr + (size_t)n * 256 + ch0);
  int o0 = off[n], o1 = off[n + 1];
  float m = -3.4e38f, s = 0.f;
  float4 a4 = {0.f, 0.f, 0.f, 0.f};
  int t = o0;
  for (; t + 2 <= o1; t += 2) {
    int sA = src_csr[t], sB = src_csr[t + 1];
    float4 xlA = *(const float4*)(xl + (size_t)sA * 256 + ch0);
    float4 xlB = *(const float4*)(xl + (size_t)sB * 256 + ch0);
    const float4* efp = (const float4*)(ef_csr + (size_t)t * 32);
    float4 evA = {0.f, 0.f, 0.f, 0.f}, evB = {0.f, 0.f, 0.f, 0.f};
#pragma unroll
    for (int q = 0; q < 8; ++q) {
      float4 fA = efp[q];
      float4 fB = efp[8 + q];
      FMA4(evA, fA.x, w4[4 * q + 0]); FMA4(evA, fA.y, w4[4 * q + 1]);
      FMA4(evA, fA.z, w4[4 * q + 2]); FMA4(evA, fA.w, w4[4 * q + 3]);
      FMA4(evB, fB.x, w4[4 * q + 0]); FMA4(evB, fB.y, w4[4 * q + 1]);
      FMA4(evB, fB.z, w4[4 * q + 2]); FMA4(evB, fB.w, w4[4 * q + 3]);
    }
    float pA = leaky_f(xlA.x + xr4.x + evA.x) * att4.x
             + leaky_f(xlA.y + xr4.y + evA.y) * att4.y
             + leaky_f(xlA.z + xr4.z + evA.z) * att4.z
             + leaky_f(xlA.w + xr4.w + evA.w) * att4.w;
    float pB = leaky_f(xlB.x + xr4.x + evB.x) * att4.x
             + leaky_f(xlB.y + xr4.y + evB.y) * att4.y
             + leaky_f(xlB.z + xr4.z + evB.z) * att4.z
             + leaky_f(xlB.w + xr4.w + evB.w) * att4.w;
#pragma unroll
    for (int d = 1; d < 16; d <<= 1) {
      pA += __shfl_xor(pA, d);
      pB += __shfl_xor(pB, d);
    }
    float nm = fmaxf(m, fmaxf(pA, pB));
    float sc = __expf(m - nm);
    float wA = __expf(pA - nm);
    float wB = __expf(pB - nm);
    s = s * sc + wA + wB;
    a4.x = a4.x * sc + wA * xlA.x + wB * xlB.x;
    a4.y = a4.y * sc + wA * xlA.y + wB * xlB.y;
    a4.z = a4.z * sc + wA * xlA.z + wB * xlB.z;
    a4.w = a4.w * sc + wA * xlA.w + wB * xlB.w;
    m = nm;
  }
  if (t < o1) {  // tail edge
    int sA = src_csr[t];
    float4 xlA = *(const float4*)(xl + (size_t)sA * 256 + ch0);
    const float4* efp = (const float4*)(ef_csr + (size_t)t * 32);
    float4 evA = {0.f, 0.f, 0.f, 0.f};
#pragma unroll
    for (int q = 0; q < 8; ++q) {
      float4 fA = efp[q];
      FMA4(evA, fA.x, w4[4 * q + 0]); FMA4(evA, fA.y, w4[4 * q + 1]);
      FMA4(evA, fA.z, w4[4 * q + 2]); FMA4(evA, fA.w, w4[4 * q + 3]);
    }
    float pA = leaky_f(xlA.x + xr4.x + evA.x) * att4.x
             + leaky_f(xlA.y + xr4.y + evA.y) * att4.y
             + leaky_f(xlA.z + xr4.z + evA.z) * att4.z
             + leaky_f(xlA.w + xr4.w + evA.w) * att4.w;
#pragma unroll
    for (int d = 1; d < 16; d <<= 1) pA += __shfl_xor(pA, d);
    float nm = fmaxf(m, pA);
    float sc = __expf(m - nm);
    float wA = __expf(pA - nm);
    s = s * sc + wA;
    a4.x = a4.x * sc + wA * xlA.x;
    a4.y = a4.y * sc + wA * xlA.y;
    a4.z = a4.z * sc + wA * xlA.z;
    a4.w = a4.w * sc + wA * xlA.w;
    m = nm;
  }
  float inv = (o1 > o0) ? 1.f / s : 0.f;
  float4 cb4 = *(const float4*)(convb + ch0);
  float4 v4;
  v4.x = a4.x * inv + cb4.x;
  v4.y = a4.y * inv + cb4.y;
  v4.z = a4.z * inv + cb4.z;
  v4.w = a4.w * inv + cb4.w;
  float ssum = v4.x + v4.y + v4.z + v4.w;
  float ssq = v4.x * v4.x + v4.y * v4.y + v4.z * v4.z + v4.w * v4.w;
#pragma unroll
  for (int d = 1; d < 64; d <<= 1) {
    ssum += __shfl_xor(ssum, d);
    ssq += __shfl_xor(ssq, d);
  }
  float mu = ssum * (1.0f / 256.0f);
  float var = ssq * (1.0f / 256.0f) - mu * mu;
  float rstd = rsqrtf(var + 1e-5f);
  float4 g4 = *(const float4*)(lng + ch0);
  float4 b4 = *(const float4*)(lnb + ch0);
  float4 xp4 = *(const float4*)(xprev + (size_t)n * 256 + ch0);
  float4 out4;
  out4.x = fmaxf((v4.x - mu) * rstd * g4.x + b4.x, 0.f) + xp4.x;
  out4.y = fmaxf((v4.y - mu) * rstd * g4.y + b4.y, 0.f) + xp4.y;
  out4.z = fmaxf((v4.z - mu) * rstd * g4.z + b4.z, 0.f) + xp4.z;
  out4.w = fmaxf((v4.w - mu) * rstd * g4.w + b4.w, 0.f) + xp4.w;
  *(float4*)(xout + (size_t)n * 256 + ch0) = out4;
}

// ---------------- output projection ----------------
__global__ __launch_bounds__(256) void k_out(
    const float* __restrict__ x, const float* __restrict__ W1, const float* __restrict__ b1,
    const float* __restrict__ W2, const float* __restrict__ b2,
    float* __restrict__ out, int N) {
  __shared__ float sW1[256 * 64];  // 64 KB
  for (int i = threadIdx.x; i < 256 * 64; i += 256) sW1[i] = W1[i];
  __syncthreads();
  int lane = threadIdx.x & 63;
  int wv = threadIdx.x >> 6;
  for (int n = blockIdx.x * 4 + wv; n < N; n += gridDim.x * 4) {
    const float* xrow = x + (size_t)n * 256;
    float h = b1[lane];
    for (int k = 0; k < 256; ++k) h += xrow[k] * sW1[k * 64 + lane];
    h = fmaxf(h, 0.f);
    float y[5];
#pragma unroll
    for (int o = 0; o < 5; ++o) {
      float p = h * W2[lane * 5 + o];
#pragma unroll
      for (int d = 1; d < 64; d <<= 1) p += __shfl_xor(p, d);
      y[o] = p;
    }
    if (lane == 0) {
#pragma unroll
      for (int o = 0; o < 5; ++o) out[(size_t)n * 5 + o] = y[o] + b2[o];
    }
  }
}

extern "C" void kernel_launch(void* const* d_in, const int* in_sizes, int n_in,
                              void* d_out, int out_size, void* d_ws, size_t ws_size,
                              hipStream_t stream) {
  const float* nf      = (const float*)d_in[0];
  const float* gf      = (const float*)d_in[1];
  const int*   eidx    = (const int*)d_in[2];
  const float* pos     = (const float*)d_in[3];
  const float* ip_W    = (const float*)d_in[4];
  const float* ip_b    = (const float*)d_in[5];
  const float* film_gW = (const float*)d_in[6];
  const float* film_gb = (const float*)d_in[7];
  const float* film_bW = (const float*)d_in[8];
  const float* film_bb = (const float*)d_in[9];
  const float* ee_W1   = (const float*)d_in[10];
  const float* ee_b1   = (const float*)d_in[11];
  const float* ee_W2   = (const float*)d_in[12];
  const float* ee_b2   = (const float*)d_in[13];
  const float* res_W   = (const float*)d_in[14];
  const float* res_b   = (const float*)d_in[15];
  const float* l0_Wl   = (const float*)d_in[16];
  const float* l0_bl   = (const float*)d_in[17];
  const float* l0_Wr   = (const float*)d_in[18];
  const float* l0_br   = (const float*)d_in[19];
  const float* Wl      = (const float*)d_in[20];
  const float* bl      = (const float*)d_in[21];
  const float* Wr      = (const float*)d_in[22];
  const float* br      = (const float*)d_in[23];
  const float* We      = (const float*)d_in[24];
  const float* att     = (const float*)d_in[25];
  const float* conv_b  = (const float*)d_in[26];
  const float* ln_g    = (const float*)d_in[27];
  const float* ln_b    = (const float*)d_in[28];
  const float* op_W1   = (const float*)d_in[29];
  const float* op_b1   = (const float*)d_in[30];
  const float* op_W2   = (const float*)d_in[31];
  const float* op_b2   = (const float*)d_in[32];

  const int N = in_sizes[0] / 5;
  const int E = in_sizes[2] / 2;
  const int* src = eidx;
  const int* dst = eidx + E;

  float* ws = (float*)d_ws;
  size_t o = 0;
  auto alloc = [&](size_t nflt) {
    float* p = ws + o;
    o += (nflt + 63) & ~(size_t)63;
    return p;
  };
  float* gb      = alloc(128);
  float* x64     = alloc((size_t)N * 64);
  float* ef_csr  = alloc((size_t)E * 32);
  int*   src_csr = (int*)alloc((size_t)E);
  int*   cnt     = (int*)alloc(2 * (size_t)N);
  int*   cur     = cnt + N;
  int*   csroff  = (int*)alloc((size_t)N + 1);
  int*   csreid  = (int*)alloc((size_t)E);
  float* xl      = alloc((size_t)N * 256);
  float* xr      = alloc((size_t)N * 256);
  float* xA      = alloc((size_t)N * 256);
  float* xB      = alloc((size_t)N * 256);
  float* xp0     = alloc((size_t)N * 256);

  (void)ws_size; (void)n_in; (void)out_size;

  hipMemsetAsync(cnt, 0, 2 * (size_t)N * sizeof(int), stream);

  k_film<<<1, 64, 0, stream>>>(gf, film_gW, film_gb, film_bW, film_bb, gb);
  k_input<<<(N + 3) / 4, 256, 0, stream>>>(nf, ip_W, ip_b, gb, x64, N);
  k_count<<<(E + 255) / 256, 256, 0, stream>>>(dst, cnt, E);
  k_scan<<<1, 256, 0, stream>>>(cnt, csroff, N);
  k_scatter<<<(E + 255) / 256, 256, 0, stream>>>(dst, csroff, cur, csreid, E);
  k_edgefeat<<<(E + 255) / 256, 256, 0, stream>>>(pos, src, dst, csreid,
      ee_W1, ee_b1, ee_W2, ee_b2, ef_csr, src_csr, E);

  const float* xin = x64;
  for (int layer = 0; layer < 6; ++layer) {
    const int K = (layer == 0) ? 64 : 256;
    const float* Wl_p = (layer == 0) ? l0_Wl : (Wl + (size_t)(layer - 1) * 256 * 256);
    const float* bl_p = (layer == 0) ? l0_bl : (bl + (size_t)(layer - 1) * 256);
    const float* Wr_p = (layer == 0) ? l0_Wr : (Wr + (size_t)(layer - 1) * 256 * 256);
    const float* br_p = (layer == 0) ? l0_br : (br + (size_t)(layer - 1) * 256);

    dim3 gg((N + 63) / 64, 4);
    k_gemm<<<gg, 256, 0, stream>>>(xin, Wl_p, bl_p, xl, N, K);
    k_gemm<<<gg, 256, 0, stream>>>(xin, Wr_p, br_p, xr, N, K);

    const float* prev;
    if (layer == 0) {
      k_gemm<<<gg, 256, 0, stream>>>(xin, res_W, res_b, xp0, N, 64);
      prev = xp0;
    } else {
      prev = xin;
    }

    float* xout = (layer & 1) ? xB : xA;
    k_fused<<<(N + 3) / 4, 256, 0, stream>>>(
        csroff, src_csr, ef_csr, xl, xr, prev,
        We + (size_t)layer * 32 * 256, att + (size_t)layer * 256,
        conv_b + (size_t)layer * 256, ln_g + (size_t)layer * 256, ln_b + (size_t)layer * 256,
        xout, N);
    xin = xout;
  }

  k_out<<<512, 256, 0, stream>>>(xin, op_W1, op_b1, op_W2, op_b2, (float*)d_out, N);
}

// Round 4
// 1315.363 us; speedup vs baseline: 2.4392x; 1.1455x over previous
//
#include <hip/hip_runtime.h>
#include <cmath>

#define DEV static __device__ __forceinline__

typedef _Float16 half_t;
typedef _Float16 half2_t __attribute__((ext_vector_type(2)));

DEV float leaky_f(float x) { return x > 0.f ? x : 0.2f * x; }

// ---------------- FiLM ----------------
__global__ void k_film(const float* __restrict__ gf,
                       const float* __restrict__ gW, const float* __restrict__ gb,
                       const float* __restrict__ bW, const float* __restrict__ bb,
                       float* __restrict__ out) {
  int j = threadIdx.x;
  if (j >= 64) return;
  float g = gb[j], b = bb[j];
  for (int k = 0; k < 128; ++k) {
    float v = gf[k];
    g += v * gW[k * 64 + j];
    b += v * bW[k * 64 + j];
  }
  out[j] = 1.0f + g;
  out[64 + j] = b;
}

// ---------------- input projection + FiLM ----------------
__global__ __launch_bounds__(256) void k_input(
    const float* __restrict__ nf, const float* __restrict__ ipW,
    const float* __restrict__ ipb, const float* __restrict__ gbv,
    float* __restrict__ x64, int N) {
  int lane = threadIdx.x & 63;
  int n = blockIdx.x * 4 + (threadIdx.x >> 6);
  if (n >= N) return;
  const float* row = nf + (size_t)n * 5;
  float acc = ipb[lane];
#pragma unroll
  for (int k = 0; k < 5; ++k) acc += row[k] * ipW[k * 64 + lane];
  acc = fmaxf(acc, 0.f);
  acc = acc * gbv[lane] + gbv[64 + lane];
  x64[(size_t)n * 64 + lane] = acc;
}

// ---------------- CSR build ----------------
__global__ void k_count(const int* __restrict__ dst, int* __restrict__ cnt, int E) {
  int e = blockIdx.x * 256 + threadIdx.x;
  if (e < E) atomicAdd(&cnt[dst[e]], 1);
}

__global__ void k_scan(const int* __restrict__ cnt, int* __restrict__ off, int N) {
  __shared__ int s[256];
  int tid = threadIdx.x;
  int carry = 0;
  for (int base = 0; base < N; base += 256) {
    int i = base + tid;
    int v = (i < N) ? cnt[i] : 0;
    __syncthreads();
    s[tid] = v;
    __syncthreads();
    int x = v;
    for (int d = 1; d < 256; d <<= 1) {
      int t = (tid >= d) ? s[tid - d] : 0;
      __syncthreads();
      x += t;
      s[tid] = x;
      __syncthreads();
    }
    if (i < N) off[i] = carry + x - v;
    carry += s[255];
  }
  if (tid == 0) off[N] = carry;
}

__global__ void k_scatter(const int* __restrict__ dst, const int* __restrict__ off,
                          int* __restrict__ cur, int* __restrict__ eid, int E) {
  int e = blockIdx.x * 256 + threadIdx.x;
  if (e < E) {
    int d = dst[e];
    int p = atomicAdd(&cur[d], 1);
    eid[off[d] + p] = e;
  }
}

// ---------------- edge encoder -> CSR order, half precision output ----------------
__global__ __launch_bounds__(256) void k_edgefeat(
    const float* __restrict__ pos, const int* __restrict__ src, const int* __restrict__ dst,
    const int* __restrict__ eid,
    const float* __restrict__ W1, const float* __restrict__ b1,
    const float* __restrict__ W2, const float* __restrict__ b2,
    half_t* __restrict__ ef_csr, int* __restrict__ src_csr, int E) {
  __shared__ float sW1[160], sb1[32], sW2[1024], sb2[32];
  for (int i = threadIdx.x; i < 160; i += 256) sW1[i] = W1[i];
  for (int i = threadIdx.x; i < 1024; i += 256) sW2[i] = W2[i];
  if (threadIdx.x < 32) { sb1[threadIdx.x] = b1[threadIdx.x]; sb2[threadIdx.x] = b2[threadIdx.x]; }
  __syncthreads();
  int t = blockIdx.x * 256 + threadIdx.x;
  if (t >= E) return;
  int e = eid[t];
  int s = src[e], d = dst[e];
  src_csr[t] = s;
  float dx = pos[d * 3 + 0] - pos[s * 3 + 0];
  float dy = pos[d * 3 + 1] - pos[s * 3 + 1];
  float dz = pos[d * 3 + 2] - pos[s * 3 + 2];
  float dist = sqrtf(dx * dx + dy * dy + dz * dz);
  dist = fmaxf(dist, 1e-6f);
  float inv = 1.f / dist;
  float attr[5] = {dx * inv, dy * inv, dz * inv, dist, logf(dist)};
  float h[32];
#pragma unroll
  for (int j = 0; j < 32; ++j) {
    float a = sb1[j];
#pragma unroll
    for (int k = 0; k < 5; ++k) a += attr[k] * sW1[k * 32 + j];
    h[j] = fmaxf(a, 0.f);
  }
  half_t hv[32];
#pragma unroll 4
  for (int j = 0; j < 32; ++j) {
    float a = sb2[j];
#pragma unroll
    for (int k = 0; k < 32; ++k) a += h[k] * sW2[k * 32 + j];
    hv[j] = (half_t)a;
  }
  uint4* ov = (uint4*)(ef_csr + (size_t)t * 32);
  const uint4* iv = (const uint4*)hv;
  ov[0] = iv[0]; ov[1] = iv[1]; ov[2] = iv[2]; ov[3] = iv[3];
}

// ---------------- tiled fp32 GEMM: C[M x 256] = A[M x K] @ B[K x 256] + bias ----------------
__global__ __launch_bounds__(256) void k_gemm(
    const float* __restrict__ A, const float* __restrict__ B,
    const float* __restrict__ bias, float* __restrict__ C, int M, int K) {
  __shared__ float As[16][64];
  __shared__ float Bs[16][68];
  int tid = threadIdx.x;
  int tx = tid & 15, ty = tid >> 4;
  int brow = blockIdx.x * 64, bcol = blockIdx.y * 64;
  float acc[4][4] = {};
  for (int k0 = 0; k0 < K; k0 += 16) {
    {
      int idx = tid * 4;
      int r = idx >> 4, kk = idx & 15;
      int row = brow + r; if (row > M - 1) row = M - 1;
      const float4 a4 = *(const float4*)(A + (size_t)row * K + k0 + kk);
      As[kk + 0][r] = a4.x; As[kk + 1][r] = a4.y; As[kk + 2][r] = a4.z; As[kk + 3][r] = a4.w;
    }
    {
      int kk = tid >> 4;
      int c = (tid & 15) * 4;
      const float4 b4 = *(const float4*)(B + (size_t)(k0 + kk) * 256 + bcol + c);
      *(float4*)(&Bs[kk][c]) = b4;
    }
    __syncthreads();
#pragma unroll
    for (int k = 0; k < 16; ++k) {
      float a[4], b[4];
#pragma unroll
      for (int i = 0; i < 4; ++i) a[i] = As[k][ty * 4 + i];
#pragma unroll
      for (int j = 0; j < 4; ++j) b[j] = Bs[k][tx * 4 + j];
#pragma unroll
      for (int i = 0; i < 4; ++i)
#pragma unroll
        for (int j = 0; j < 4; ++j) acc[i][j] += a[i] * b[j];
    }
    __syncthreads();
  }
#pragma unroll
  for (int i = 0; i < 4; ++i) {
    int row = brow + ty * 4 + i;
    if (row < M) {
      float4 r;
      r.x = acc[i][0] + bias[bcol + tx * 4 + 0];
      r.y = acc[i][1] + bias[bcol + tx * 4 + 1];
      r.z = acc[i][2] + bias[bcol + tx * 4 + 2];
      r.w = acc[i][3] + bias[bcol + tx * 4 + 3];
      *(float4*)(C + (size_t)row * 256 + bcol + tx * 4) = r;
    }
  }
}

// ---------------- fused GATv2 layer ----------------
// wave per dst node; lane owns 4 contiguous channels of head h = lane>>4.
// f16 dot2 for ef@We; max-free softmax (logits bounded << 88); 2-edge pipelined loop.
__global__ __launch_bounds__(256) void k_fused(
    const int* __restrict__ off, const int* __restrict__ src_csr,
    const half_t* __restrict__ ef_csr,
    const float* __restrict__ xl, const float* __restrict__ xr,
    const float* __restrict__ xprev,
    const float* __restrict__ We_l, const float* __restrict__ att_l,
    const float* __restrict__ convb, const float* __restrict__ lng,
    const float* __restrict__ lnb,
    float* __restrict__ xout, int N) {
  int lane = threadIdx.x & 63;
  int n = blockIdx.x * 4 + (threadIdx.x >> 6);
  if (n >= N) return;
  n = __builtin_amdgcn_readfirstlane(n);
  int h = lane >> 4, c0 = lane & 15;
  int ch0 = h * 64 + (c0 << 2);
  // We k-pairs for this lane's 4 channels as half2: w2[q][c] = (We[2q][ch0+c], We[2q+1][ch0+c])
  half2_t w2[16][4];
#pragma unroll
  for (int q = 0; q < 16; ++q) {
    float4 r0 = *(const float4*)(We_l + (size_t)(2 * q) * 256 + ch0);
    float4 r1 = *(const float4*)(We_l + (size_t)(2 * q + 1) * 256 + ch0);
    w2[q][0] = half2_t{(half_t)r0.x, (half_t)r1.x};
    w2[q][1] = half2_t{(half_t)r0.y, (half_t)r1.y};
    w2[q][2] = half2_t{(half_t)r0.z, (half_t)r1.z};
    w2[q][3] = half2_t{(half_t)r0.w, (half_t)r1.w};
  }
  float4 att4 = *(const float4*)(att_l + ch0);
  float4 xr4 = *(const float4*)(xr + (size_t)n * 256 + ch0);
  int o0 = off[n], o1 = off[n + 1];
  int deg = o1 - o0;
  float s = 0.f;
  float4 a4 = {0.f, 0.f, 0.f, 0.f};

#define GATE(T, XL, P)                                                              \
  {                                                                                 \
    const half2_t* efp = (const half2_t*)(ef_csr + (size_t)(T) * 32);               \
    float e0 = 0.f, e1 = 0.f, e2 = 0.f, e3 = 0.f;                                   \
    _Pragma("unroll") for (int q = 0; q < 16; ++q) {                                \
      half2_t f = efp[q];                                                           \
      e0 = __builtin_amdgcn_fdot2(f, w2[q][0], e0, false);                          \
      e1 = __builtin_amdgcn_fdot2(f, w2[q][1], e1, false);                          \
      e2 = __builtin_amdgcn_fdot2(f, w2[q][2], e2, false);                          \
      e3 = __builtin_amdgcn_fdot2(f, w2[q][3], e3, false);                          \
    }                                                                               \
    P = leaky_f((XL).x + xr4.x + e0) * att4.x + leaky_f((XL).y + xr4.y + e1) * att4.y \
      + leaky_f((XL).z + xr4.z + e2) * att4.z + leaky_f((XL).w + xr4.w + e3) * att4.w; \
  }

  int npairs = deg >> 1;
  int t = o0;
  if (npairs > 0) {
    int sA = src_csr[t], sB = src_csr[t + 1];
    float4 xlA = *(const float4*)(xl + (size_t)sA * 256 + ch0);
    float4 xlB = *(const float4*)(xl + (size_t)sB * 256 + ch0);
    for (int p = 0; p < npairs - 1; ++p, t += 2) {
      // prefetch next pair
      int sC = src_csr[t + 2], sD = src_csr[t + 3];
      float4 xlC = *(const float4*)(xl + (size_t)sC * 256 + ch0);
      float4 xlD = *(const float4*)(xl + (size_t)sD * 256 + ch0);
      float pA, pB;
      GATE(t, xlA, pA);
      GATE(t + 1, xlB, pB);
#pragma unroll
      for (int d = 1; d < 16; d <<= 1) {
        pA += __shfl_xor(pA, d);
        pB += __shfl_xor(pB, d);
      }
      float wA = __expf(pA), wB = __expf(pB);
      s += wA + wB;
      a4.x += wA * xlA.x + wB * xlB.x;
      a4.y += wA * xlA.y + wB * xlB.y;
      a4.z += wA * xlA.z + wB * xlB.z;
      a4.w += wA * xlA.w + wB * xlB.w;
      xlA = xlC; xlB = xlD;
    }
    {  // last full pair
      float pA, pB;
      GATE(t, xlA, pA);
      GATE(t + 1, xlB, pB);
#pragma unroll
      for (int d = 1; d < 16; d <<= 1) {
        pA += __shfl_xor(pA, d);
        pB += __shfl_xor(pB, d);
      }
      float wA = __expf(pA), wB = __expf(pB);
      s += wA + wB;
      a4.x += wA * xlA.x + wB * xlB.x;
      a4.y += wA * xlA.y + wB * xlB.y;
      a4.z += wA * xlA.z + wB * xlB.z;
      a4.w += wA * xlA.w + wB * xlB.w;
      t += 2;
    }
  }
  if (t < o1) {  // odd tail edge
    int sA = src_csr[t];
    float4 xlA = *(const float4*)(xl + (size_t)sA * 256 + ch0);
    float pA;
    GATE(t, xlA, pA);
#pragma unroll
    for (int d = 1; d < 16; d <<= 1) pA += __shfl_xor(pA, d);
    float wA = __expf(pA);
    s += wA;
    a4.x += wA * xlA.x;
    a4.y += wA * xlA.y;
    a4.z += wA * xlA.z;
    a4.w += wA * xlA.w;
  }
#undef GATE

  float inv = (deg > 0) ? 1.f / s : 0.f;
  float4 cb4 = *(const float4*)(convb + ch0);
  float4 v4;
  v4.x = a4.x * inv + cb4.x;
  v4.y = a4.y * inv + cb4.y;
  v4.z = a4.z * inv + cb4.z;
  v4.w = a4.w * inv + cb4.w;
  float ssum = v4.x + v4.y + v4.z + v4.w;
  float ssq = v4.x * v4.x + v4.y * v4.y + v4.z * v4.z + v4.w * v4.w;
#pragma unroll
  for (int d = 1; d < 64; d <<= 1) {
    ssum += __shfl_xor(ssum, d);
    ssq += __shfl_xor(ssq, d);
  }
  float mu = ssum * (1.0f / 256.0f);
  float var = ssq * (1.0f / 256.0f) - mu * mu;
  float rstd = rsqrtf(var + 1e-5f);
  float4 g4 = *(const float4*)(lng + ch0);
  float4 b4 = *(const float4*)(lnb + ch0);
  float4 xp4 = *(const float4*)(xprev + (size_t)n * 256 + ch0);
  float4 out4;
  out4.x = fmaxf((v4.x - mu) * rstd * g4.x + b4.x, 0.f) + xp4.x;
  out4.y = fmaxf((v4.y - mu) * rstd * g4.y + b4.y, 0.f) + xp4.y;
  out4.z = fmaxf((v4.z - mu) * rstd * g4.z + b4.z, 0.f) + xp4.z;
  out4.w = fmaxf((v4.w - mu) * rstd * g4.w + b4.w, 0.f) + xp4.w;
  *(float4*)(xout + (size_t)n * 256 + ch0) = out4;
}

// ---------------- output projection ----------------
__global__ __launch_bounds__(256) void k_out(
    const float* __restrict__ x, const float* __restrict__ W1, const float* __restrict__ b1,
    const float* __restrict__ W2, const float* __restrict__ b2,
    float* __restrict__ out, int N) {
  __shared__ float sW1[256 * 64];  // 64 KB
  for (int i = threadIdx.x; i < 256 * 64; i += 256) sW1[i] = W1[i];
  __syncthreads();
  int lane = threadIdx.x & 63;
  int wv = threadIdx.x >> 6;
  for (int n = blockIdx.x * 4 + wv; n < N; n += gridDim.x * 4) {
    const float* xrow = x + (size_t)n * 256;
    float h = b1[lane];
    for (int k = 0; k < 256; ++k) h += xrow[k] * sW1[k * 64 + lane];
    h = fmaxf(h, 0.f);
    float y[5];
#pragma unroll
    for (int o = 0; o < 5; ++o) {
      float p = h * W2[lane * 5 + o];
#pragma unroll
      for (int d = 1; d < 64; d <<= 1) p += __shfl_xor(p, d);
      y[o] = p;
    }
    if (lane == 0) {
#pragma unroll
      for (int o = 0; o < 5; ++o) out[(size_t)n * 5 + o] = y[o] + b2[o];
    }
  }
}

extern "C" void kernel_launch(void* const* d_in, const int* in_sizes, int n_in,
                              void* d_out, int out_size, void* d_ws, size_t ws_size,
                              hipStream_t stream) {
  const float* nf      = (const float*)d_in[0];
  const float* gf      = (const float*)d_in[1];
  const int*   eidx    = (const int*)d_in[2];
  const float* pos     = (const float*)d_in[3];
  const float* ip_W    = (const float*)d_in[4];
  const float* ip_b    = (const float*)d_in[5];
  const float* film_gW = (const float*)d_in[6];
  const float* film_gb = (const float*)d_in[7];
  const float* film_bW = (const float*)d_in[8];
  const float* film_bb = (const float*)d_in[9];
  const float* ee_W1   = (const float*)d_in[10];
  const float* ee_b1   = (const float*)d_in[11];
  const float* ee_W2   = (const float*)d_in[12];
  const float* ee_b2   = (const float*)d_in[13];
  const float* res_W   = (const float*)d_in[14];
  const float* res_b   = (const float*)d_in[15];
  const float* l0_Wl   = (const float*)d_in[16];
  const float* l0_bl   = (const float*)d_in[17];
  const float* l0_Wr   = (const float*)d_in[18];
  const float* l0_br   = (const float*)d_in[19];
  const float* Wl      = (const float*)d_in[20];
  const float* bl      = (const float*)d_in[21];
  const float* Wr      = (const float*)d_in[22];
  const float* br      = (const float*)d_in[23];
  const float* We      = (const float*)d_in[24];
  const float* att     = (const float*)d_in[25];
  const float* conv_b  = (const float*)d_in[26];
  const float* ln_g    = (const float*)d_in[27];
  const float* ln_b    = (const float*)d_in[28];
  const float* op_W1   = (const float*)d_in[29];
  const float* op_b1   = (const float*)d_in[30];
  const float* op_W2   = (const float*)d_in[31];
  const float* op_b2   = (const float*)d_in[32];

  const int N = in_sizes[0] / 5;
  const int E = in_sizes[2] / 2;
  const int* src = eidx;
  const int* dst = eidx + E;

  float* ws = (float*)d_ws;
  size_t o = 0;
  auto alloc = [&](size_t nflt) {
    float* p = ws + o;
    o += (nflt + 63) & ~(size_t)63;
    return p;
  };
  float* gb      = alloc(128);
  float* x64     = alloc((size_t)N * 64);
  half_t* ef_csr = (half_t*)alloc((size_t)E * 16);  // E*32 halfs
  int*   src_csr = (int*)alloc((size_t)E);
  int*   cnt     = (int*)alloc(2 * (size_t)N);
  int*   cur     = cnt + N;
  int*   csroff  = (int*)alloc((size_t)N + 1);
  int*   csreid  = (int*)alloc((size_t)E);
  float* xl      = alloc((size_t)N * 256);
  float* xr      = alloc((size_t)N * 256);
  float* xA      = alloc((size_t)N * 256);
  float* xB      = alloc((size_t)N * 256);
  float* xp0     = alloc((size_t)N * 256);

  (void)ws_size; (void)n_in; (void)out_size;

  hipMemsetAsync(cnt, 0, 2 * (size_t)N * sizeof(int), stream);

  k_film<<<1, 64, 0, stream>>>(gf, film_gW, film_gb, film_bW, film_bb, gb);
  k_input<<<(N + 3) / 4, 256, 0, stream>>>(nf, ip_W, ip_b, gb, x64, N);
  k_count<<<(E + 255) / 256, 256, 0, stream>>>(dst, cnt, E);
  k_scan<<<1, 256, 0, stream>>>(cnt, csroff, N);
  k_scatter<<<(E + 255) / 256, 256, 0, stream>>>(dst, csroff, cur, csreid, E);
  k_edgefeat<<<(E + 255) / 256, 256, 0, stream>>>(pos, src, dst, csreid,
      ee_W1, ee_b1, ee_W2, ee_b2, ef_csr, src_csr, E);

  const float* xin = x64;
  for (int layer = 0; layer < 6; ++layer) {
    const int K = (layer == 0) ? 64 : 256;
    const float* Wl_p = (layer == 0) ? l0_Wl : (Wl + (size_t)(layer - 1) * 256 * 256);
    const float* bl_p = (layer == 0) ? l0_bl : (bl + (size_t)(layer - 1) * 256);
    const float* Wr_p = (layer == 0) ? l0_Wr : (Wr + (size_t)(layer - 1) * 256 * 256);
    const float* br_p = (layer == 0) ? l0_br : (br + (size_t)(layer - 1) * 256);

    dim3 gg((N + 63) / 64, 4);
    k_gemm<<<gg, 256, 0, stream>>>(xin, Wl_p, bl_p, xl, N, K);
    k_gemm<<<gg, 256, 0, stream>>>(xin, Wr_p, br_p, xr, N, K);

    const float* prev;
    if (layer == 0) {
      k_gemm<<<gg, 256, 0, stream>>>(xin, res_W, res_b, xp0, N, 64);
      prev = xp0;
    } else {
      prev = xin;
    }

    float* xout = (layer & 1) ? xB : xA;
    k_fused<<<(N + 3) / 4, 256, 0, stream>>>(
        csroff, src_csr, ef_csr, xl, xr, prev,
        We + (size_t)layer * 32 * 256, att + (size_t)layer * 256,
        conv_b + (size_t)layer * 256, ln_g + (size_t)layer * 256, ln_b + (size_t)layer * 256,
        xout, N);
    xin = xout;
  }

  k_out<<<512, 256, 0, stream>>>(xin, op_W1, op_b1, op_W2, op_b2, (float*)d_out, N);
}

// Round 5
// 1255.102 us; speedup vs baseline: 2.5563x; 1.0480x over previous
//
#include <hip/hip_runtime.h>
#include <cmath>

#define DEV static __device__ __forceinline__

typedef _Float16 half_t;
typedef _Float16 half2_t __attribute__((ext_vector_type(2)));
typedef _Float16 half8_t __attribute__((ext_vector_type(8)));
typedef float f32x4 __attribute__((ext_vector_type(4)));

DEV float leaky_f(float x) { return x > 0.f ? x : 0.2f * x; }

// ---------------- FiLM ----------------
__global__ void k_film(const float* __restrict__ gf,
                       const float* __restrict__ gW, const float* __restrict__ gb,
                       const float* __restrict__ bW, const float* __restrict__ bb,
                       float* __restrict__ out) {
  int j = threadIdx.x;
  if (j >= 64) return;
  float g = gb[j], b = bb[j];
  for (int k = 0; k < 128; ++k) {
    float v = gf[k];
    g += v * gW[k * 64 + j];
    b += v * bW[k * 64 + j];
  }
  out[j] = 1.0f + g;
  out[64 + j] = b;
}

// ---------------- input projection + FiLM ----------------
__global__ __launch_bounds__(256) void k_input(
    const float* __restrict__ nf, const float* __restrict__ ipW,
    const float* __restrict__ ipb, const float* __restrict__ gbv,
    float* __restrict__ x64, int N) {
  int lane = threadIdx.x & 63;
  int n = blockIdx.x * 4 + (threadIdx.x >> 6);
  if (n >= N) return;
  const float* row = nf + (size_t)n * 5;
  float acc = ipb[lane];
#pragma unroll
  for (int k = 0; k < 5; ++k) acc += row[k] * ipW[k * 64 + lane];
  acc = fmaxf(acc, 0.f);
  acc = acc * gbv[lane] + gbv[64 + lane];
  x64[(size_t)n * 64 + lane] = acc;
}

// ---------------- CSR build ----------------
__global__ void k_count(const int* __restrict__ dst, int* __restrict__ cnt, int E) {
  int e = blockIdx.x * 256 + threadIdx.x;
  if (e < E) atomicAdd(&cnt[dst[e]], 1);
}

__global__ void k_scan(const int* __restrict__ cnt, int* __restrict__ off, int N) {
  __shared__ int s[256];
  int tid = threadIdx.x;
  int carry = 0;
  for (int base = 0; base < N; base += 256) {
    int i = base + tid;
    int v = (i < N) ? cnt[i] : 0;
    __syncthreads();
    s[tid] = v;
    __syncthreads();
    int x = v;
    for (int d = 1; d < 256; d <<= 1) {
      int t = (tid >= d) ? s[tid - d] : 0;
      __syncthreads();
      x += t;
      s[tid] = x;
      __syncthreads();
    }
    if (i < N) off[i] = carry + x - v;
    carry += s[255];
  }
  if (tid == 0) off[N] = carry;
}

__global__ void k_scatter(const int* __restrict__ dst, const int* __restrict__ off,
                          int* __restrict__ cur, int* __restrict__ eid, int E) {
  int e = blockIdx.x * 256 + threadIdx.x;
  if (e < E) {
    int d = dst[e];
    int p = atomicAdd(&cur[d], 1);
    eid[off[d] + p] = e;
  }
}

// ---------------- edge encoder -> CSR order, half precision output ----------------
__global__ __launch_bounds__(256) void k_edgefeat(
    const float* __restrict__ pos, const int* __restrict__ src, const int* __restrict__ dst,
    const int* __restrict__ eid,
    const float* __restrict__ W1, const float* __restrict__ b1,
    const float* __restrict__ W2, const float* __restrict__ b2,
    half_t* __restrict__ ef_csr, int* __restrict__ src_csr, int E) {
  __shared__ float sW1[160], sb1[32], sW2[1024], sb2[32];
  for (int i = threadIdx.x; i < 160; i += 256) sW1[i] = W1[i];
  for (int i = threadIdx.x; i < 1024; i += 256) sW2[i] = W2[i];
  if (threadIdx.x < 32) { sb1[threadIdx.x] = b1[threadIdx.x]; sb2[threadIdx.x] = b2[threadIdx.x]; }
  __syncthreads();
  int t = blockIdx.x * 256 + threadIdx.x;
  if (t >= E) return;
  int e = eid[t];
  int s = src[e], d = dst[e];
  src_csr[t] = s;
  float dx = pos[d * 3 + 0] - pos[s * 3 + 0];
  float dy = pos[d * 3 + 1] - pos[s * 3 + 1];
  float dz = pos[d * 3 + 2] - pos[s * 3 + 2];
  float dist = sqrtf(dx * dx + dy * dy + dz * dz);
  dist = fmaxf(dist, 1e-6f);
  float inv = 1.f / dist;
  float attr[5] = {dx * inv, dy * inv, dz * inv, dist, logf(dist)};
  float h[32];
#pragma unroll
  for (int j = 0; j < 32; ++j) {
    float a = sb1[j];
#pragma unroll
    for (int k = 0; k < 5; ++k) a += attr[k] * sW1[k * 32 + j];
    h[j] = fmaxf(a, 0.f);
  }
  half_t hv[32];
#pragma unroll 4
  for (int j = 0; j < 32; ++j) {
    float a = sb2[j];
#pragma unroll
    for (int k = 0; k < 32; ++k) a += h[k] * sW2[k * 32 + j];
    hv[j] = (half_t)a;
  }
  uint4* ov = (uint4*)(ef_csr + (size_t)t * 32);
  const uint4* iv = (const uint4*)hv;
  ov[0] = iv[0]; ov[1] = iv[1]; ov[2] = iv[2]; ov[3] = iv[3];
}

// ---------------- weight prep: W (K x 256) fp32 -> Bt (256 x K) f16 ----------------
__global__ __launch_bounds__(256) void k_prepB(const float* __restrict__ W,
                                               half_t* __restrict__ Bt, int K) {
  int i = blockIdx.x * 256 + threadIdx.x;
  if (i < K * 256) {
    int k = i >> 8, c = i & 255;
    Bt[(size_t)c * K + k] = (half_t)W[i];
  }
}

// ---------------- MFMA f16 GEMM: C[M x 256] = A[M x K] @ B[K x 256] + bias ----------------
// block = 4 waves; wave w owns rows [bx*64 + w*16, +16), cols [by*64, +64) as 4 16-col tiles.
// No LDS: A loaded fp32->f16 in-register; B-frags straight from pre-transposed f16 Bt (L2-hot).
__global__ __launch_bounds__(256) void k_gemm16(
    const float* __restrict__ A, const half_t* __restrict__ Bt,
    const float* __restrict__ bias, float* __restrict__ C, int M, int K) {
  int w = threadIdx.x >> 6, lane = threadIdx.x & 63;
  int r16 = lane & 15, kg = lane >> 4;             // kg = k-group 0..3
  int arow = blockIdx.x * 64 + w * 16 + r16;
  int arowc = arow < M ? arow : M - 1;
  int bcol = blockIdx.y * 64;
  f32x4 acc[4] = {};
  const int nks = K >> 5;
  const float* ap = A + (size_t)arowc * K + kg * 8;
  for (int ks = 0; ks < nks; ++ks) {
    float4 a0 = *(const float4*)(ap + ks * 32);
    float4 a1 = *(const float4*)(ap + ks * 32 + 4);
    half8_t af;
    af[0] = (half_t)a0.x; af[1] = (half_t)a0.y; af[2] = (half_t)a0.z; af[3] = (half_t)a0.w;
    af[4] = (half_t)a1.x; af[5] = (half_t)a1.y; af[6] = (half_t)a1.z; af[7] = (half_t)a1.w;
    int k0 = ks * 32 + kg * 8;
#pragma unroll
    for (int nt = 0; nt < 4; ++nt) {
      half8_t bf = *(const half8_t*)(Bt + (size_t)(bcol + nt * 16 + r16) * K + k0);
      acc[nt] = __builtin_amdgcn_mfma_f32_16x16x32_f16(af, bf, acc[nt], 0, 0, 0);
    }
  }
  // C/D layout: col = lane&15, row = (lane>>4)*4 + reg
  int orow0 = blockIdx.x * 64 + w * 16 + kg * 4;
#pragma unroll
  for (int nt = 0; nt < 4; ++nt) {
    int gcol = bcol + nt * 16 + r16;
    float bv = bias[gcol];
#pragma unroll
    for (int r = 0; r < 4; ++r) {
      int grow = orow0 + r;
      if (grow < M) C[(size_t)grow * 256 + gcol] = acc[nt][r] + bv;
    }
  }
}

// ---------------- fused GATv2 layer ----------------
__global__ __launch_bounds__(256) void k_fused(
    const int* __restrict__ off, const int* __restrict__ src_csr,
    const half_t* __restrict__ ef_csr,
    const float* __restrict__ xl, const float* __restrict__ xr,
    const float* __restrict__ xprev,
    const float* __restrict__ We_l, const float* __restrict__ att_l,
    const float* __restrict__ convb, const float* __restrict__ lng,
    const float* __restrict__ lnb,
    float* __restrict__ xout, int N) {
  int lane = threadIdx.x & 63;
  int n = blockIdx.x * 4 + (threadIdx.x >> 6);
  if (n >= N) return;
  n = __builtin_amdgcn_readfirstlane(n);
  int h = lane >> 4, c0 = lane & 15;
  int ch0 = h * 64 + (c0 << 2);
  half2_t w2[16][4];
#pragma unroll
  for (int q = 0; q < 16; ++q) {
    float4 r0 = *(const float4*)(We_l + (size_t)(2 * q) * 256 + ch0);
    float4 r1 = *(const float4*)(We_l + (size_t)(2 * q + 1) * 256 + ch0);
    w2[q][0] = half2_t{(half_t)r0.x, (half_t)r1.x};
    w2[q][1] = half2_t{(half_t)r0.y, (half_t)r1.y};
    w2[q][2] = half2_t{(half_t)r0.z, (half_t)r1.z};
    w2[q][3] = half2_t{(half_t)r0.w, (half_t)r1.w};
  }
  float4 att4 = *(const float4*)(att_l + ch0);
  float4 xr4 = *(const float4*)(xr + (size_t)n * 256 + ch0);
  int o0 = off[n], o1 = off[n + 1];
  int deg = o1 - o0;
  float s = 0.f;
  float4 a4 = {0.f, 0.f, 0.f, 0.f};

#define GATE(T, XL, P)                                                              \
  {                                                                                 \
    const half2_t* efp = (const half2_t*)(ef_csr + (size_t)(T) * 32);               \
    float e0 = 0.f, e1 = 0.f, e2 = 0.f, e3 = 0.f;                                   \
    _Pragma("unroll") for (int q = 0; q < 16; ++q) {                                \
      half2_t f = efp[q];                                                           \
      e0 = __builtin_amdgcn_fdot2(f, w2[q][0], e0, false);                          \
      e1 = __builtin_amdgcn_fdot2(f, w2[q][1], e1, false);                          \
      e2 = __builtin_amdgcn_fdot2(f, w2[q][2], e2, false);                          \
      e3 = __builtin_amdgcn_fdot2(f, w2[q][3], e3, false);                          \
    }                                                                               \
    P = leaky_f((XL).x + xr4.x + e0) * att4.x + leaky_f((XL).y + xr4.y + e1) * att4.y \
      + leaky_f((XL).z + xr4.z + e2) * att4.z + leaky_f((XL).w + xr4.w + e3) * att4.w; \
  }

  int npairs = deg >> 1;
  int t = o0;
  if (npairs > 0) {
    int sA = src_csr[t], sB = src_csr[t + 1];
    float4 xlA = *(const float4*)(xl + (size_t)sA * 256 + ch0);
    float4 xlB = *(const float4*)(xl + (size_t)sB * 256 + ch0);
    for (int p = 0; p < npairs - 1; ++p, t += 2) {
      int sC = src_csr[t + 2], sD = src_csr[t + 3];
      float4 xlC = *(const float4*)(xl + (size_t)sC * 256 + ch0);
      float4 xlD = *(const float4*)(xl + (size_t)sD * 256 + ch0);
      float pA, pB;
      GATE(t, xlA, pA);
      GATE(t + 1, xlB, pB);
#pragma unroll
      for (int d = 1; d < 16; d <<= 1) {
        pA += __shfl_xor(pA, d);
        pB += __shfl_xor(pB, d);
      }
      float wA = __expf(pA), wB = __expf(pB);
      s += wA + wB;
      a4.x += wA * xlA.x + wB * xlB.x;
      a4.y += wA * xlA.y + wB * xlB.y;
      a4.z += wA * xlA.z + wB * xlB.z;
      a4.w += wA * xlA.w + wB * xlB.w;
      xlA = xlC; xlB = xlD;
    }
    {
      float pA, pB;
      GATE(t, xlA, pA);
      GATE(t + 1, xlB, pB);
#pragma unroll
      for (int d = 1; d < 16; d <<= 1) {
        pA += __shfl_xor(pA, d);
        pB += __shfl_xor(pB, d);
      }
      float wA = __expf(pA), wB = __expf(pB);
      s += wA + wB;
      a4.x += wA * xlA.x + wB * xlB.x;
      a4.y += wA * xlA.y + wB * xlB.y;
      a4.z += wA * xlA.z + wB * xlB.z;
      a4.w += wA * xlA.w + wB * xlB.w;
      t += 2;
    }
  }
  if (t < o1) {
    int sA = src_csr[t];
    float4 xlA = *(const float4*)(xl + (size_t)sA * 256 + ch0);
    float pA;
    GATE(t, xlA, pA);
#pragma unroll
    for (int d = 1; d < 16; d <<= 1) pA += __shfl_xor(pA, d);
    float wA = __expf(pA);
    s += wA;
    a4.x += wA * xlA.x;
    a4.y += wA * xlA.y;
    a4.z += wA * xlA.z;
    a4.w += wA * xlA.w;
  }
#undef GATE

  float inv = (deg > 0) ? 1.f / s : 0.f;
  float4 cb4 = *(const float4*)(convb + ch0);
  float4 v4;
  v4.x = a4.x * inv + cb4.x;
  v4.y = a4.y * inv + cb4.y;
  v4.z = a4.z * inv + cb4.z;
  v4.w = a4.w * inv + cb4.w;
  float ssum = v4.x + v4.y + v4.z + v4.w;
  float ssq = v4.x * v4.x + v4.y * v4.y + v4.z * v4.z + v4.w * v4.w;
#pragma unroll
  for (int d = 1; d < 64; d <<= 1) {
    ssum += __shfl_xor(ssum, d);
    ssq += __shfl_xor(ssq, d);
  }
  float mu = ssum * (1.0f / 256.0f);
  float var = ssq * (1.0f / 256.0f) - mu * mu;
  float rstd = rsqrtf(var + 1e-5f);
  float4 g4 = *(const float4*)(lng + ch0);
  float4 b4 = *(const float4*)(lnb + ch0);
  float4 xp4 = *(const float4*)(xprev + (size_t)n * 256 + ch0);
  float4 out4;
  out4.x = fmaxf((v4.x - mu) * rstd * g4.x + b4.x, 0.f) + xp4.x;
  out4.y = fmaxf((v4.y - mu) * rstd * g4.y + b4.y, 0.f) + xp4.y;
  out4.z = fmaxf((v4.z - mu) * rstd * g4.z + b4.z, 0.f) + xp4.z;
  out4.w = fmaxf((v4.w - mu) * rstd * g4.w + b4.w, 0.f) + xp4.w;
  *(float4*)(xout + (size_t)n * 256 + ch0) = out4;
}

// ---------------- output projection ----------------
__global__ __launch_bounds__(256) void k_out(
    const float* __restrict__ x, const float* __restrict__ W1, const float* __restrict__ b1,
    const float* __restrict__ W2, const float* __restrict__ b2,
    float* __restrict__ out, int N) {
  __shared__ float sW1[256 * 64];  // 64 KB
  for (int i = threadIdx.x; i < 256 * 64; i += 256) sW1[i] = W1[i];
  __syncthreads();
  int lane = threadIdx.x & 63;
  int wv = threadIdx.x >> 6;
  for (int n = blockIdx.x * 4 + wv; n < N; n += gridDim.x * 4) {
    const float* xrow = x + (size_t)n * 256;
    float h = b1[lane];
    for (int k = 0; k < 256; ++k) h += xrow[k] * sW1[k * 64 + lane];
    h = fmaxf(h, 0.f);
    float y[5];
#pragma unroll
    for (int o = 0; o < 5; ++o) {
      float p = h * W2[lane * 5 + o];
#pragma unroll
      for (int d = 1; d < 64; d <<= 1) p += __shfl_xor(p, d);
      y[o] = p;
    }
    if (lane == 0) {
#pragma unroll
      for (int o = 0; o < 5; ++o) out[(size_t)n * 5 + o] = y[o] + b2[o];
    }
  }
}

extern "C" void kernel_launch(void* const* d_in, const int* in_sizes, int n_in,
                              void* d_out, int out_size, void* d_ws, size_t ws_size,
                              hipStream_t stream) {
  const float* nf      = (const float*)d_in[0];
  const float* gf      = (const float*)d_in[1];
  const int*   eidx    = (const int*)d_in[2];
  const float* pos     = (const float*)d_in[3];
  const float* ip_W    = (const float*)d_in[4];
  const float* ip_b    = (const float*)d_in[5];
  const float* film_gW = (const float*)d_in[6];
  const float* film_gb = (const float*)d_in[7];
  const float* film_bW = (const float*)d_in[8];
  const float* film_bb = (const float*)d_in[9];
  const float* ee_W1   = (const float*)d_in[10];
  const float* ee_b1   = (const float*)d_in[11];
  const float* ee_W2   = (const float*)d_in[12];
  const float* ee_b2   = (const float*)d_in[13];
  const float* res_W   = (const float*)d_in[14];
  const float* res_b   = (const float*)d_in[15];
  const float* l0_Wl   = (const float*)d_in[16];
  const float* l0_bl   = (const float*)d_in[17];
  const float* l0_Wr   = (const float*)d_in[18];
  const float* l0_br   = (const float*)d_in[19];
  const float* Wl      = (const float*)d_in[20];
  const float* bl      = (const float*)d_in[21];
  const float* Wr      = (const float*)d_in[22];
  const float* br      = (const float*)d_in[23];
  const float* We      = (const float*)d_in[24];
  const float* att     = (const float*)d_in[25];
  const float* conv_b  = (const float*)d_in[26];
  const float* ln_g    = (const float*)d_in[27];
  const float* ln_b    = (const float*)d_in[28];
  const float* op_W1   = (const float*)d_in[29];
  const float* op_b1   = (const float*)d_in[30];
  const float* op_W2   = (const float*)d_in[31];
  const float* op_b2   = (const float*)d_in[32];

  const int N = in_sizes[0] / 5;
  const int E = in_sizes[2] / 2;
  const int* src = eidx;
  const int* dst = eidx + E;

  float* ws = (float*)d_ws;
  size_t o = 0;
  auto alloc = [&](size_t nflt) {
    float* p = ws + o;
    o += (nflt + 63) & ~(size_t)63;
    return p;
  };
  float* gb      = alloc(128);
  float* x64     = alloc((size_t)N * 64);
  half_t* ef_csr = (half_t*)alloc((size_t)E * 16);  // E*32 halfs
  int*   src_csr = (int*)alloc((size_t)E);
  int*   cnt     = (int*)alloc(2 * (size_t)N);
  int*   cur     = cnt + N;
  int*   csroff  = (int*)alloc((size_t)N + 1);
  int*   csreid  = (int*)alloc((size_t)E);
  float* xl      = alloc((size_t)N * 256);
  float* xr      = alloc((size_t)N * 256);
  float* xA      = alloc((size_t)N * 256);
  float* xB      = alloc((size_t)N * 256);
  float* xp0     = alloc((size_t)N * 256);
  // f16 transposed weights: 3 K=64 mats (l0_Wl, l0_Wr, res_W) + 10 K=256 mats
  half_t* btL0l  = (half_t*)alloc(256 * 64 / 2);
  half_t* btL0r  = (half_t*)alloc(256 * 64 / 2);
  half_t* btRes  = (half_t*)alloc(256 * 64 / 2);
  half_t* btWl   = (half_t*)alloc(5 * 256 * 256 / 2);
  half_t* btWr   = (half_t*)alloc(5 * 256 * 256 / 2);

  (void)ws_size; (void)n_in; (void)out_size;

  hipMemsetAsync(cnt, 0, 2 * (size_t)N * sizeof(int), stream);

  k_film<<<1, 64, 0, stream>>>(gf, film_gW, film_gb, film_bW, film_bb, gb);
  k_input<<<(N + 3) / 4, 256, 0, stream>>>(nf, ip_W, ip_b, gb, x64, N);
  k_count<<<(E + 255) / 256, 256, 0, stream>>>(dst, cnt, E);
  k_scan<<<1, 256, 0, stream>>>(cnt, csroff, N);
  k_scatter<<<(E + 255) / 256, 256, 0, stream>>>(dst, csroff, cur, csreid, E);
  k_edgefeat<<<(E + 255) / 256, 256, 0, stream>>>(pos, src, dst, csreid,
      ee_W1, ee_b1, ee_W2, ee_b2, ef_csr, src_csr, E);

  // weight prep (f16 transpose)
  const int g64 = (64 * 256 + 255) / 256, g256 = (256 * 256 + 255) / 256;
  k_prepB<<<g64, 256, 0, stream>>>(l0_Wl, btL0l, 64);
  k_prepB<<<g64, 256, 0, stream>>>(l0_Wr, btL0r, 64);
  k_prepB<<<g64, 256, 0, stream>>>(res_W, btRes, 64);
  for (int i = 0; i < 5; ++i) {
    k_prepB<<<g256, 256, 0, stream>>>(Wl + (size_t)i * 256 * 256, btWl + (size_t)i * 256 * 256, 256);
    k_prepB<<<g256, 256, 0, stream>>>(Wr + (size_t)i * 256 * 256, btWr + (size_t)i * 256 * 256, 256);
  }

  dim3 gg((N + 63) / 64, 4);
  const float* xin = x64;
  for (int layer = 0; layer < 6; ++layer) {
    const int K = (layer == 0) ? 64 : 256;
    const half_t* btl = (layer == 0) ? btL0l : (btWl + (size_t)(layer - 1) * 256 * 256);
    const half_t* btr = (layer == 0) ? btL0r : (btWr + (size_t)(layer - 1) * 256 * 256);
    const float* bl_p = (layer == 0) ? l0_bl : (bl + (size_t)(layer - 1) * 256);
    const float* br_p = (layer == 0) ? l0_br : (br + (size_t)(layer - 1) * 256);

    k_gemm16<<<gg, 256, 0, stream>>>(xin, btl, bl_p, xl, N, K);
    k_gemm16<<<gg, 256, 0, stream>>>(xin, btr, br_p, xr, N, K);

    const float* prev;
    if (layer == 0) {
      k_gemm16<<<gg, 256, 0, stream>>>(xin, btRes, res_b, xp0, N, 64);
      prev = xp0;
    } else {
      prev = xin;
    }

    float* xout = (layer & 1) ? xB : xA;
    k_fused<<<(N + 3) / 4, 256, 0, stream>>>(
        csroff, src_csr, ef_csr, xl, xr, prev,
        We + (size_t)layer * 32 * 256, att + (size_t)layer * 256,
        conv_b + (size_t)layer * 256, ln_g + (size_t)layer * 256, ln_b + (size_t)layer * 256,
        xout, N);
    xin = xout;
  }

  k_out<<<512, 256, 0, stream>>>(xin, op_W1, op_b1, op_W2, op_b2, (float*)d_out, N);
}